// Round 1
// baseline (1008.633 us; speedup 1.0000x reference)
//
#include <hip/hip_runtime.h>
#include <hip/hip_bf16.h>
#include <stdint.h>

// Shape2DPainterNet forward: LSTM(64 steps, D=64) + heads + JAX-exact categorical sampling.
// B=16384, T=64, D=64, V+1=32001 (all derived from in_sizes at launch).

// ---------------- threefry2x32 (bit-exact JAX impl) ----------------
__device__ __forceinline__ uint32_t rotl32(uint32_t x, uint32_t r) {
  return (x << r) | (x >> (32u - r));
}

__device__ __forceinline__ uint2 threefry2x32(uint32_t k0, uint32_t k1,
                                              uint32_t x0, uint32_t x1) {
  const uint32_t k2 = k0 ^ k1 ^ 0x1BD11BDAu;
  x0 += k0; x1 += k1;
#define TFR(r) { x0 += x1; x1 = rotl32(x1, r); x1 ^= x0; }
  TFR(13u) TFR(15u) TFR(26u) TFR(6u)
  x0 += k1; x1 += k2 + 1u;
  TFR(17u) TFR(29u) TFR(16u) TFR(24u)
  x0 += k2; x1 += k0 + 2u;
  TFR(13u) TFR(15u) TFR(26u) TFR(6u)
  x0 += k0; x1 += k1 + 3u;
  TFR(17u) TFR(29u) TFR(16u) TFR(24u)
  x0 += k1; x1 += k2 + 4u;
  TFR(13u) TFR(15u) TFR(26u) TFR(6u)
  x0 += k2; x1 += k0 + 5u;
#undef TFR
  return make_uint2(x0, x1);
}

// gumbel(key, shape)[flat_idx]; partitionable counters (JAX >= 0.4.36 default):
// bits = x0 ^ x1 of threefry(key, (hi=0, lo=flat_idx)).
__device__ __forceinline__ float gumbel_jax(uint32_t k0, uint32_t k1, uint32_t idx) {
  uint2 o = threefry2x32(k0, k1, 0u, idx);
  uint32_t bits = o.x ^ o.y;
  float f = __uint_as_float(0x3f800000u | (bits >> 9)) - 1.0f;   // [0,1)
  const float tiny = 1.1754943508222875e-38f;                    // finfo(f32).tiny
  float u = fmaxf(tiny, f + tiny);   // f*(maxval-minval)+minval, (1-tiny) rounds to 1.0f
  return -logf(-logf(u));
}

// categorical + log_softmax-at-sample. Mirrors argmax(logits + gumbel) (first max wins)
// and lp = l[s] - max(l) - log(sum(exp(l - max))).
template <int C>
__device__ __forceinline__ void sample_head(const float* lg, uint32_t k0, uint32_t k1,
                                            int row, int& samp, float& lp) {
  float best = -3.402823466e38f;
  int bi = 0;
  float lsel = lg[0];
  float m = lg[0];
  #pragma unroll
  for (int c = 0; c < C; ++c) {
    float t = lg[c] + gumbel_jax(k0, k1, (uint32_t)(row * C + c));
    if (t > best) { best = t; bi = c; lsel = lg[c]; }
    m = fmaxf(m, lg[c]);
  }
  float s = 0.f;
  #pragma unroll
  for (int c = 0; c < C; ++c) s += expf(lg[c] - m);
  samp = bi;
  lp = lsel - m - logf(s);
}

__device__ __forceinline__ float sigmoidf_(float x) { return 1.0f / (1.0f + expf(-x)); }

// ---------------- Kernel 1: embedW[v][d][gi] = (embed @ W_ih + b_ih + b_hh), gate-grouped ----
// Layout: embedW[v*256 + d*4 + gi] where source column g = gi*64 + d (torch i,f,g,o chunks).
__global__ __launch_bounds__(1024) void k_embedw(
    const float* __restrict__ embed, const float* __restrict__ W_ih,
    const float* __restrict__ b_ih, const float* __restrict__ b_hh,
    float* __restrict__ embedWG, int NV) {
  __shared__ float sW[64 * 256];            // W_ih[k][g], 64 KB
  const int tid = threadIdx.x;
  for (int i = tid; i < 4096; i += 1024)
    ((float4*)sW)[i] = ((const float4*)W_ih)[i];
  __syncthreads();
  const int d   = tid & 63;                 // lane-consecutive -> conflict-free sW reads
  const int gi  = (tid >> 6) & 3;
  const int vr0 = tid >> 8;                 // 0..3
  const int g   = gi * 64 + d;
  const float bias = b_ih[g] + b_hh[g];
  const int vbase = blockIdx.x * 126;
  for (int it = 0; it < 32; ++it) {
    int lr = it * 4 + vr0;
    int v  = vbase + lr;
    if (lr < 126 && v < NV) {
      const float* e = embed + (size_t)v * 64;
      float acc = bias;
      #pragma unroll 8
      for (int k = 0; k < 64; ++k) acc = fmaf(e[k], sW[k * 256 + g], acc);
      embedWG[(size_t)v * 256 + d * 4 + gi] = acc;
    }
  }
}

// ---------------- Kernel 2: LSTM, 64 steps, f32 VALU ----------------
// 1 block = 64 batch rows. lane l = row; wave wid owns units d0..d0+3.
// LDS: sW = W_hh gate-grouped [d][k][gi] (64 KB, wave-uniform b128 reads = broadcast),
//      sH = h^T [unit][row]   (16 KB, lane-consecutive b32 reads = conflict-free).
__global__ __launch_bounds__(1024) void k_lstm64(
    const int* __restrict__ inst, const float* __restrict__ W_hh,
    const float* __restrict__ embedWG, float* __restrict__ eOut) {
  extern __shared__ float smem[];
  float* sW = smem;             // 16384 floats
  float* sH = smem + 16384;     // 4096 floats

  const int tid = threadIdx.x;
  const int l   = tid & 63;
  const int wid = tid >> 6;
  const int d0  = wid << 2;
  const int rbase = blockIdx.x << 6;
  const size_t r  = (size_t)rbase + l;

  for (int i = tid; i < 16384; i += 1024) {
    int k = i >> 8, g = i & 255;
    sW[(g & 63) * 256 + k * 4 + (g >> 6)] = W_hh[i];   // [d][k][gi]
  }
  for (int i = tid; i < 4096; i += 1024) sH[i] = 0.f;
  __syncthreads();

  float c[4] = {0.f, 0.f, 0.f, 0.f};
  float4 gc[4], gn[4];
  int tok1;
  {
    int tok0 = inst[r * 64 + 0];
    tok1     = inst[r * 64 + 1];
    const float4* p = (const float4*)(embedWG + (size_t)tok0 * 256 + d0 * 4);
    #pragma unroll
    for (int i = 0; i < 4; ++i) gc[i] = p[i];
  }

  const float4* wv = (const float4*)sW;   // float4 index: d*64 + k

  for (int t = 0; t < 64; ++t) {
    // prefetch gates(t+1) and token(t+2); consumed after barrier2 -> latency hidden
    {
      const float4* p = (const float4*)(embedWG + (size_t)tok1 * 256 + d0 * 4);
      #pragma unroll
      for (int i = 0; i < 4; ++i) gn[i] = p[i];
    }
    int tok2 = inst[r * 64 + (t + 2 < 64 ? t + 2 : 63)];

    float a[4][4];
    #pragma unroll
    for (int u = 0; u < 4; ++u) {
      a[u][0] = gc[u].x; a[u][1] = gc[u].y; a[u][2] = gc[u].z; a[u][3] = gc[u].w;
    }

    #pragma unroll 4
    for (int k = 0; k < 64; ++k) {
      float hk = sH[k * 64 + l];
      #pragma unroll
      for (int u = 0; u < 4; ++u) {
        float4 w = wv[(d0 + u) * 64 + k];
        a[u][0] = fmaf(hk, w.x, a[u][0]);
        a[u][1] = fmaf(hk, w.y, a[u][1]);
        a[u][2] = fmaf(hk, w.z, a[u][2]);
        a[u][3] = fmaf(hk, w.w, a[u][3]);
      }
    }
    __syncthreads();                     // everyone done reading sH(t)
    #pragma unroll
    for (int u = 0; u < 4; ++u) {        // torch gate order i,f,g,o
      float ig = sigmoidf_(a[u][0]);
      float fg = sigmoidf_(a[u][1]);
      float gg = tanhf(a[u][2]);
      float og = sigmoidf_(a[u][3]);
      float cn = fg * c[u] + ig * gg;
      c[u] = cn;
      sH[(d0 + u) * 64 + l] = og * tanhf(cn);
    }
    __syncthreads();                     // sH(t+1) visible to all
    #pragma unroll
    for (int i = 0; i < 4; ++i) gc[i] = gn[i];
    tok1 = tok2;
  }

  // write final hidden state, coalesced
  for (int i = tid; i < 4096; i += 1024) {
    int rr = i >> 6, dd = i & 63;
    eOut[(size_t)(rbase + rr) * 64 + dd] = sH[dd * 64 + rr];
  }
}

// ---------------- Kernel 3: attention MLP logits, one thread per (row, cell) ----------------
__global__ __launch_bounds__(256) void k_attlog(
    const float* __restrict__ eOut, const float* __restrict__ canvas,
    const float* __restrict__ Wr1, const float* __restrict__ br1,
    const float* __restrict__ Wr2, const float* __restrict__ br2,
    float* __restrict__ attL, int total) {
  const int gid = blockIdx.x * 256 + threadIdx.x;
  if (gid >= total) return;
  const int rrow = gid / 25, cell = gid - rrow * 25;
  const float* e  = eOut + (size_t)rrow * 64;
  const float* cv = canvas + (size_t)rrow * 100 + cell * 4;
  float cv0 = cv[0], cv1 = cv[1], cv2 = cv[2], cv3 = cv[3];

  float h[32];
  #pragma unroll
  for (int j4 = 0; j4 < 8; ++j4) {
    float4 b4 = ((const float4*)br1)[j4];
    float4 w64 = ((const float4*)(Wr1 + 64 * 32))[j4];
    float4 w65 = ((const float4*)(Wr1 + 65 * 32))[j4];
    float4 w66 = ((const float4*)(Wr1 + 66 * 32))[j4];
    float4 w67 = ((const float4*)(Wr1 + 67 * 32))[j4];
    h[j4*4+0] = fmaf(cv3, w67.x, fmaf(cv2, w66.x, fmaf(cv1, w65.x, fmaf(cv0, w64.x, b4.x))));
    h[j4*4+1] = fmaf(cv3, w67.y, fmaf(cv2, w66.y, fmaf(cv1, w65.y, fmaf(cv0, w64.y, b4.y))));
    h[j4*4+2] = fmaf(cv3, w67.z, fmaf(cv2, w66.z, fmaf(cv1, w65.z, fmaf(cv0, w64.z, b4.z))));
    h[j4*4+3] = fmaf(cv3, w67.w, fmaf(cv2, w66.w, fmaf(cv1, w65.w, fmaf(cv0, w64.w, b4.w))));
  }
  for (int k = 0; k < 64; ++k) {
    float ek = e[k];
    const float4* wrow = (const float4*)(Wr1 + k * 32);
    #pragma unroll
    for (int j4 = 0; j4 < 8; ++j4) {
      float4 w = wrow[j4];
      h[j4*4+0] = fmaf(ek, w.x, h[j4*4+0]);
      h[j4*4+1] = fmaf(ek, w.y, h[j4*4+1]);
      h[j4*4+2] = fmaf(ek, w.z, h[j4*4+2]);
      h[j4*4+3] = fmaf(ek, w.w, h[j4*4+3]);
    }
  }
  float logit = br2[0];
  #pragma unroll
  for (int j = 0; j < 32; ++j) logit = fmaf(fmaxf(h[j], 0.f), Wr2[j], logit);
  attL[gid] = logit;
}

// ---------------- Kernel 4: heads + sampling + index_join, one thread per row ----------------
__global__ __launch_bounds__(256) void k_heads(
    const float* __restrict__ eOut, const float* __restrict__ canvas,
    const int* __restrict__ inst_type,
    const float* __restrict__ Wc, const float* __restrict__ bc,
    const float* __restrict__ Wsh, const float* __restrict__ bsh,
    const float* __restrict__ Wa, const float* __restrict__ ba,
    const float* __restrict__ Wl, const float* __restrict__ bl,
    const float* __restrict__ Wr, const float* __restrict__ br,
    const float* __restrict__ attL, float* __restrict__ out, int B) {
  const int r = blockIdx.x * 256 + threadIdx.x;
  if (r >= B) return;
  const float* e = eOut + (size_t)r * 64;

  // six head keys: split(key(42), 6) foldlike: key_h = threefry((0,42),(0,h))
  uint2 kc  = threefry2x32(0u, 42u, 0u, 0u);
  uint2 ksh = threefry2x32(0u, 42u, 0u, 1u);
  uint2 kac = threefry2x32(0u, 42u, 0u, 2u);
  uint2 kab = threefry2x32(0u, 42u, 0u, 3u);
  uint2 krl = threefry2x32(0u, 42u, 0u, 4u);
  uint2 kat = threefry2x32(0u, 42u, 0u, 5u);

  float lc[3]  = {bc[0], bc[1], bc[2]};
  float lsh[3] = {bsh[0], bsh[1], bsh[2]};
  float lac[2] = {ba[0], ba[1]};
  float ll[25];
  #pragma unroll
  for (int j = 0; j < 25; ++j) ll[j] = bl[j];
  float lrr[8];
  #pragma unroll
  for (int j = 0; j < 8; ++j) lrr[j] = br[j];

  for (int k = 0; k < 64; ++k) {          // rolled k keeps code small; acc arrays in regs
    float ek = e[k];
    #pragma unroll
    for (int j = 0; j < 3; ++j)  lc[j]  = fmaf(ek, Wc[k * 3 + j],  lc[j]);
    #pragma unroll
    for (int j = 0; j < 3; ++j)  lsh[j] = fmaf(ek, Wsh[k * 3 + j], lsh[j]);
    #pragma unroll
    for (int j = 0; j < 2; ++j)  lac[j] = fmaf(ek, Wa[k * 2 + j],  lac[j]);
    #pragma unroll
    for (int j = 0; j < 25; ++j) ll[j]  = fmaf(ek, Wl[k * 25 + j], ll[j]);
    #pragma unroll
    for (int j = 0; j < 8; ++j)  lrr[j] = fmaf(ek, Wr[k * 8 + j],  lrr[j]);
  }

  int s_color, s_shape, s_act, s_abs, s_rel, s_att;
  float lp_color, lp_shape, lp_act, lp_abs, lp_rel, lp_att;
  sample_head<3>(lc,  kc.x,  kc.y,  r, s_color, lp_color);
  sample_head<3>(lsh, ksh.x, ksh.y, r, s_shape, lp_shape);
  sample_head<2>(lac, kac.x, kac.y, r, s_act,   lp_act);
  sample_head<25>(ll, kab.x, kab.y, r, s_abs,   lp_abs);
  sample_head<8>(lrr, krl.x, krl.y, r, s_rel,   lp_rel);

  float lat[25];
  #pragma unroll
  for (int j = 0; j < 25; ++j) lat[j] = attL[(size_t)r * 25 + j];
  sample_head<25>(lat, kat.x, kat.y, r, s_att, lp_att);

  // ref object gather + relative location
  const float* cvp = canvas + (size_t)r * 100 + s_att * 4;
  int ref_r = (int)cvp[2];
  int ref_c = (int)cvp[3];
  // offsets [[-1,0],[1,0],[0,1],[0,-1],[-1,-1],[-1,1],[1,-1],[1,1]] packed as nibbles (+1)
  int dr = (int)((0x22001120u >> (4 * s_rel)) & 15u) - 1;
  int dc = (int)((0x20200211u >> (4 * s_rel)) & 15u) - 1;
  int rel_loc = (ref_r + dr) * 5 + (ref_c + dc);

  bool isrel = (inst_type[r] == 2);
  out[(size_t)r * 5 + 0] = lp_color;
  out[(size_t)r * 5 + 1] = lp_shape;
  out[(size_t)r * 5 + 2] = lp_act;
  out[(size_t)r * 5 + 3] = isrel ? lp_rel : lp_abs;
  out[(size_t)r * 5 + 4] = isrel ? lp_att : 0.f;
  out[(size_t)B * 5 + r] = (float)(isrel ? rel_loc : s_abs);
}

// ---------------- launch ----------------
extern "C" void kernel_launch(void* const* d_in, const int* in_sizes, int n_in,
                              void* d_out, int out_size, void* d_ws, size_t ws_size,
                              hipStream_t stream) {
  (void)n_in; (void)out_size; (void)ws_size;
  const int*   inst      = (const int*)  d_in[0];
  const float* canvas    = (const float*)d_in[1];
  const int*   inst_type = (const int*)  d_in[2];
  const float* embed     = (const float*)d_in[3];
  const float* W_ih      = (const float*)d_in[4];
  const float* W_hh      = (const float*)d_in[5];
  const float* b_ih      = (const float*)d_in[6];
  const float* b_hh      = (const float*)d_in[7];
  const float* Wc  = (const float*)d_in[8];  const float* bc  = (const float*)d_in[9];
  const float* Wsh = (const float*)d_in[10]; const float* bsh = (const float*)d_in[11];
  const float* Wa  = (const float*)d_in[12]; const float* ba  = (const float*)d_in[13];
  const float* Wl  = (const float*)d_in[14]; const float* bl  = (const float*)d_in[15];
  const float* Wr  = (const float*)d_in[16]; const float* br  = (const float*)d_in[17];
  const float* Wr1 = (const float*)d_in[18]; const float* br1 = (const float*)d_in[19];
  const float* Wr2 = (const float*)d_in[20]; const float* br2 = (const float*)d_in[21];

  const int B  = in_sizes[0] / 64;   // 16384
  const int NV = in_sizes[3] / 64;   // 32001

  // workspace: embedW (NV*256 f32 ~31.3MB) | eOut (B*64 ~4MB) | attL (B*25 ~1.6MB)
  float* embedWG = (float*)d_ws;
  float* eOut    = embedWG + (size_t)NV * 256;
  float* attL    = eOut + (size_t)B * 64;
  float* out     = (float*)d_out;

  // 80 KB dynamic LDS for the LSTM kernel
  hipFuncSetAttribute((const void*)k_lstm64,
                      hipFuncAttributeMaxDynamicSharedMemorySize, 81920);

  k_embedw<<<(NV + 125) / 126, 1024, 0, stream>>>(embed, W_ih, b_ih, b_hh, embedWG, NV);
  k_lstm64<<<B / 64, 1024, 81920, stream>>>(inst, W_hh, embedWG, eOut);
  {
    int total = B * 25;
    k_attlog<<<(total + 255) / 256, 256, 0, stream>>>(eOut, canvas, Wr1, br1, Wr2, br2,
                                                      attL, total);
  }
  k_heads<<<(B + 255) / 256, 256, 0, stream>>>(eOut, canvas, inst_type,
                                               Wc, bc, Wsh, bsh, Wa, ba, Wl, bl, Wr, br,
                                               attL, out, B);
}

// Round 3
// 841.455 us; speedup vs baseline: 1.1987x; 1.1987x over previous
//
#include <hip/hip_runtime.h>
#include <hip/hip_bf16.h>
#include <stdint.h>

// Shape2DPainterNet forward: LSTM(64 steps, D=64) + heads + JAX-exact categorical sampling.
// B=16384, T=64, D=64, V+1=32001 (all derived from in_sizes at launch).
//
// R2 change (re-submitted; R2 bench timed out before running): W_hh no longer staged in
// LDS (wave-uniform b128 broadcasts cost full LDS bandwidth -> 4096 instr/CU/step was
// the bottleneck). W_hh is pre-transposed to [k][unit][gate] and read via uniform
// s_load into SGPRs (scalar pipe, one 64B fetch per wave per k, reused by all 64
// lanes). Accumulation order and nonlinearity are bit-identical to the passing R1 kernel.

// ---------------- threefry2x32 (bit-exact JAX impl) ----------------
__device__ __forceinline__ uint32_t rotl32(uint32_t x, uint32_t r) {
  return (x << r) | (x >> (32u - r));
}

__device__ __forceinline__ uint2 threefry2x32(uint32_t k0, uint32_t k1,
                                              uint32_t x0, uint32_t x1) {
  const uint32_t k2 = k0 ^ k1 ^ 0x1BD11BDAu;
  x0 += k0; x1 += k1;
#define TFR(r) { x0 += x1; x1 = rotl32(x1, r); x1 ^= x0; }
  TFR(13u) TFR(15u) TFR(26u) TFR(6u)
  x0 += k1; x1 += k2 + 1u;
  TFR(17u) TFR(29u) TFR(16u) TFR(24u)
  x0 += k2; x1 += k0 + 2u;
  TFR(13u) TFR(15u) TFR(26u) TFR(6u)
  x0 += k0; x1 += k1 + 3u;
  TFR(17u) TFR(29u) TFR(16u) TFR(24u)
  x0 += k1; x1 += k2 + 4u;
  TFR(13u) TFR(15u) TFR(26u) TFR(6u)
  x0 += k2; x1 += k0 + 5u;
#undef TFR
  return make_uint2(x0, x1);
}

// gumbel(key, shape)[flat_idx]; partitionable counters (JAX >= 0.4.36 default):
// bits = x0 ^ x1 of threefry(key, (hi=0, lo=flat_idx)).
__device__ __forceinline__ float gumbel_jax(uint32_t k0, uint32_t k1, uint32_t idx) {
  uint2 o = threefry2x32(k0, k1, 0u, idx);
  uint32_t bits = o.x ^ o.y;
  float f = __uint_as_float(0x3f800000u | (bits >> 9)) - 1.0f;   // [0,1)
  const float tiny = 1.1754943508222875e-38f;                    // finfo(f32).tiny
  float u = fmaxf(tiny, f + tiny);
  return -logf(-logf(u));
}

template <int C>
__device__ __forceinline__ void sample_head(const float* lg, uint32_t k0, uint32_t k1,
                                            int row, int& samp, float& lp) {
  float best = -3.402823466e38f;
  int bi = 0;
  float lsel = lg[0];
  float m = lg[0];
  #pragma unroll
  for (int c = 0; c < C; ++c) {
    float t = lg[c] + gumbel_jax(k0, k1, (uint32_t)(row * C + c));
    if (t > best) { best = t; bi = c; lsel = lg[c]; }
    m = fmaxf(m, lg[c]);
  }
  float s = 0.f;
  #pragma unroll
  for (int c = 0; c < C; ++c) s += expf(lg[c] - m);
  samp = bi;
  lp = lsel - m - logf(s);
}

__device__ __forceinline__ float sigmoidf_(float x) { return 1.0f / (1.0f + expf(-x)); }

// ---------------- Kernel 1: embedW[v][d][gi] = (embed @ W_ih + b_ih + b_hh) ----------------
// Layout: embedW[v*256 + d*4 + gi] where source column g = gi*64 + d (torch i,f,g,o chunks).
__global__ __launch_bounds__(1024) void k_embedw(
    const float* __restrict__ embed, const float* __restrict__ W_ih,
    const float* __restrict__ b_ih, const float* __restrict__ b_hh,
    float* __restrict__ embedWG, int NV) {
  __shared__ float sW[64 * 256];            // W_ih[k][g], 64 KB
  const int tid = threadIdx.x;
  for (int i = tid; i < 4096; i += 1024)
    ((float4*)sW)[i] = ((const float4*)W_ih)[i];
  __syncthreads();
  const int d   = tid & 63;                 // lane-consecutive -> conflict-free sW reads
  const int gi  = (tid >> 6) & 3;
  const int vr0 = tid >> 8;                 // 0..3
  const int g   = gi * 64 + d;
  const float bias = b_ih[g] + b_hh[g];
  const int vbase = blockIdx.x * 126;
  for (int it = 0; it < 32; ++it) {
    int lr = it * 4 + vr0;
    int v  = vbase + lr;
    if (lr < 126 && v < NV) {
      const float* e = embed + (size_t)v * 64;
      float acc = bias;
      #pragma unroll 8
      for (int k = 0; k < 64; ++k) acc = fmaf(e[k], sW[k * 256 + g], acc);
      embedWG[(size_t)v * 256 + d * 4 + gi] = acc;
    }
  }
}

// ---------------- Kernel 1b: wt[k*256 + u*4 + gi] = W_hh[k*256 + gi*64 + u] ------------
__global__ __launch_bounds__(1024) void k_wt(const float* __restrict__ W_hh,
                                             float* __restrict__ wt) {
  const int idx = blockIdx.x * 1024 + threadIdx.x;   // 16 blocks x 1024 = 16384
  if (idx < 16384) {
    const int k = idx >> 8, g = idx & 255;
    const int gi = g >> 6, u = g & 63;
    wt[k * 256 + u * 4 + gi] = W_hh[idx];
  }
}

// ---------------- Kernel 2: LSTM, 64 steps, f32 VALU, W via SGPRs ----------------
// 1 block = 64 batch rows. lane l = row; wave wid owns units d0..d0+3.
// LDS: sH = h^T [unit][row] (16 KB, lane-consecutive b32 -> conflict-free).
// W: uniform s_load per k from wt (uniform address via readfirstlane), FMA reads SGPR.
__global__ __launch_bounds__(1024) void k_lstm64(
    const int* __restrict__ inst, const float* __restrict__ wt,
    const float* __restrict__ embedWG, float* __restrict__ eOut) {
  __shared__ float sH[4096];

  const int tid = threadIdx.x;
  const int l   = tid & 63;
  const int wid = tid >> 6;
  const int d0  = wid << 2;
  const int rbase = blockIdx.x << 6;
  const size_t r  = (size_t)rbase + l;

  // wave-uniform W base: wave wid needs wt[k*256 + wid*16 + j], j in [0,16)
  const float* __restrict__ wp = wt + __builtin_amdgcn_readfirstlane(wid * 16);

  for (int i = tid; i < 4096; i += 1024) sH[i] = 0.f;
  __syncthreads();

  float c[4] = {0.f, 0.f, 0.f, 0.f};
  float4 gc[4], gn[4];
  int tok1;
  {
    int tok0 = inst[r * 64 + 0];
    tok1     = inst[r * 64 + 1];
    const float4* p = (const float4*)(embedWG + (size_t)tok0 * 256 + d0 * 4);
    #pragma unroll
    for (int i = 0; i < 4; ++i) gc[i] = p[i];
  }

  for (int t = 0; t < 64; ++t) {
    // prefetch gates(t+1) and token(t+2); consumed after barrier2 -> latency hidden
    {
      const float4* p = (const float4*)(embedWG + (size_t)tok1 * 256 + d0 * 4);
      #pragma unroll
      for (int i = 0; i < 4; ++i) gn[i] = p[i];
    }
    int tok2 = inst[r * 64 + (t + 2 < 64 ? t + 2 : 63)];

    float a[4][4];
    #pragma unroll
    for (int u = 0; u < 4; ++u) {
      a[u][0] = gc[u].x; a[u][1] = gc[u].y; a[u][2] = gc[u].z; a[u][3] = gc[u].w;
    }

    #pragma unroll 4
    for (int k = 0; k < 64; ++k) {
      float hk = sH[k * 64 + l];                 // lane-consecutive b32, conflict-free
      const float* __restrict__ wk = wp + k * 256;  // uniform -> s_load
      #pragma unroll
      for (int j = 0; j < 16; ++j)
        a[j >> 2][j & 3] = fmaf(hk, wk[j], a[j >> 2][j & 3]);
    }
    __syncthreads();                     // everyone done reading sH(t)
    #pragma unroll
    for (int u = 0; u < 4; ++u) {        // torch gate order i,f,g,o
      float ig = sigmoidf_(a[u][0]);
      float fg = sigmoidf_(a[u][1]);
      float gg = tanhf(a[u][2]);
      float og = sigmoidf_(a[u][3]);
      float cn = fg * c[u] + ig * gg;
      c[u] = cn;
      sH[(d0 + u) * 64 + l] = og * tanhf(cn);
    }
    __syncthreads();                     // sH(t+1) visible to all
    #pragma unroll
    for (int i = 0; i < 4; ++i) gc[i] = gn[i];
    tok1 = tok2;
  }

  // write final hidden state, coalesced
  for (int i = tid; i < 4096; i += 1024) {
    int rr = i >> 6, dd = i & 63;
    eOut[(size_t)(rbase + rr) * 64 + dd] = sH[dd * 64 + rr];
  }
}

// ---------------- Kernel 3: attention MLP logits, one thread per (row, cell) ----------------
__global__ __launch_bounds__(256) void k_attlog(
    const float* __restrict__ eOut, const float* __restrict__ canvas,
    const float* __restrict__ Wr1, const float* __restrict__ br1,
    const float* __restrict__ Wr2, const float* __restrict__ br2,
    float* __restrict__ attL, int total) {
  const int gid = blockIdx.x * 256 + threadIdx.x;
  if (gid >= total) return;
  const int rrow = gid / 25, cell = gid - rrow * 25;
  const float* e  = eOut + (size_t)rrow * 64;
  const float* cv = canvas + (size_t)rrow * 100 + cell * 4;
  float cv0 = cv[0], cv1 = cv[1], cv2 = cv[2], cv3 = cv[3];

  float h[32];
  #pragma unroll
  for (int j4 = 0; j4 < 8; ++j4) {
    float4 b4 = ((const float4*)br1)[j4];
    float4 w64 = ((const float4*)(Wr1 + 64 * 32))[j4];
    float4 w65 = ((const float4*)(Wr1 + 65 * 32))[j4];
    float4 w66 = ((const float4*)(Wr1 + 66 * 32))[j4];
    float4 w67 = ((const float4*)(Wr1 + 67 * 32))[j4];
    h[j4*4+0] = fmaf(cv3, w67.x, fmaf(cv2, w66.x, fmaf(cv1, w65.x, fmaf(cv0, w64.x, b4.x))));
    h[j4*4+1] = fmaf(cv3, w67.y, fmaf(cv2, w66.y, fmaf(cv1, w65.y, fmaf(cv0, w64.y, b4.y))));
    h[j4*4+2] = fmaf(cv3, w67.z, fmaf(cv2, w66.z, fmaf(cv1, w65.z, fmaf(cv0, w64.z, b4.z))));
    h[j4*4+3] = fmaf(cv3, w67.w, fmaf(cv2, w66.w, fmaf(cv1, w65.w, fmaf(cv0, w64.w, b4.w))));
  }
  for (int k = 0; k < 64; ++k) {
    float ek = e[k];
    const float4* wrow = (const float4*)(Wr1 + k * 32);
    #pragma unroll
    for (int j4 = 0; j4 < 8; ++j4) {
      float4 w = wrow[j4];
      h[j4*4+0] = fmaf(ek, w.x, h[j4*4+0]);
      h[j4*4+1] = fmaf(ek, w.y, h[j4*4+1]);
      h[j4*4+2] = fmaf(ek, w.z, h[j4*4+2]);
      h[j4*4+3] = fmaf(ek, w.w, h[j4*4+3]);
    }
  }
  float logit = br2[0];
  #pragma unroll
  for (int j = 0; j < 32; ++j) logit = fmaf(fmaxf(h[j], 0.f), Wr2[j], logit);
  attL[gid] = logit;
}

// ---------------- Kernel 4: heads + sampling + index_join, one thread per row ----------------
__global__ __launch_bounds__(256) void k_heads(
    const float* __restrict__ eOut, const float* __restrict__ canvas,
    const int* __restrict__ inst_type,
    const float* __restrict__ Wc, const float* __restrict__ bc,
    const float* __restrict__ Wsh, const float* __restrict__ bsh,
    const float* __restrict__ Wa, const float* __restrict__ ba,
    const float* __restrict__ Wl, const float* __restrict__ bl,
    const float* __restrict__ Wr, const float* __restrict__ br,
    const float* __restrict__ attL, float* __restrict__ out, int B) {
  const int r = blockIdx.x * 256 + threadIdx.x;
  if (r >= B) return;
  const float* e = eOut + (size_t)r * 64;

  uint2 kc  = threefry2x32(0u, 42u, 0u, 0u);
  uint2 ksh = threefry2x32(0u, 42u, 0u, 1u);
  uint2 kac = threefry2x32(0u, 42u, 0u, 2u);
  uint2 kab = threefry2x32(0u, 42u, 0u, 3u);
  uint2 krl = threefry2x32(0u, 42u, 0u, 4u);
  uint2 kat = threefry2x32(0u, 42u, 0u, 5u);

  float lc[3]  = {bc[0], bc[1], bc[2]};
  float lsh[3] = {bsh[0], bsh[1], bsh[2]};
  float lac[2] = {ba[0], ba[1]};
  float ll[25];
  #pragma unroll
  for (int j = 0; j < 25; ++j) ll[j] = bl[j];
  float lrr[8];
  #pragma unroll
  for (int j = 0; j < 8; ++j) lrr[j] = br[j];

  for (int k = 0; k < 64; ++k) {
    float ek = e[k];
    #pragma unroll
    for (int j = 0; j < 3; ++j)  lc[j]  = fmaf(ek, Wc[k * 3 + j],  lc[j]);
    #pragma unroll
    for (int j = 0; j < 3; ++j)  lsh[j] = fmaf(ek, Wsh[k * 3 + j], lsh[j]);
    #pragma unroll
    for (int j = 0; j < 2; ++j)  lac[j] = fmaf(ek, Wa[k * 2 + j],  lac[j]);
    #pragma unroll
    for (int j = 0; j < 25; ++j) ll[j]  = fmaf(ek, Wl[k * 25 + j], ll[j]);
    #pragma unroll
    for (int j = 0; j < 8; ++j)  lrr[j] = fmaf(ek, Wr[k * 8 + j],  lrr[j]);
  }

  int s_color, s_shape, s_act, s_abs, s_rel, s_att;
  float lp_color, lp_shape, lp_act, lp_abs, lp_rel, lp_att;
  sample_head<3>(lc,  kc.x,  kc.y,  r, s_color, lp_color);
  sample_head<3>(lsh, ksh.x, ksh.y, r, s_shape, lp_shape);
  sample_head<2>(lac, kac.x, kac.y, r, s_act,   lp_act);
  sample_head<25>(ll, kab.x, kab.y, r, s_abs,   lp_abs);
  sample_head<8>(lrr, krl.x, krl.y, r, s_rel,   lp_rel);

  float lat[25];
  #pragma unroll
  for (int j = 0; j < 25; ++j) lat[j] = attL[(size_t)r * 25 + j];
  sample_head<25>(lat, kat.x, kat.y, r, s_att, lp_att);

  const float* cvp = canvas + (size_t)r * 100 + s_att * 4;
  int ref_r = (int)cvp[2];
  int ref_c = (int)cvp[3];
  int dr = (int)((0x22001120u >> (4 * s_rel)) & 15u) - 1;
  int dc = (int)((0x20200211u >> (4 * s_rel)) & 15u) - 1;
  int rel_loc = (ref_r + dr) * 5 + (ref_c + dc);

  bool isrel = (inst_type[r] == 2);
  out[(size_t)r * 5 + 0] = lp_color;
  out[(size_t)r * 5 + 1] = lp_shape;
  out[(size_t)r * 5 + 2] = lp_act;
  out[(size_t)r * 5 + 3] = isrel ? lp_rel : lp_abs;
  out[(size_t)r * 5 + 4] = isrel ? lp_att : 0.f;
  out[(size_t)B * 5 + r] = (float)(isrel ? rel_loc : s_abs);
}

// ---------------- launch ----------------
extern "C" void kernel_launch(void* const* d_in, const int* in_sizes, int n_in,
                              void* d_out, int out_size, void* d_ws, size_t ws_size,
                              hipStream_t stream) {
  (void)n_in; (void)out_size; (void)ws_size;
  const int*   inst      = (const int*)  d_in[0];
  const float* canvas    = (const float*)d_in[1];
  const int*   inst_type = (const int*)  d_in[2];
  const float* embed     = (const float*)d_in[3];
  const float* W_ih      = (const float*)d_in[4];
  const float* W_hh      = (const float*)d_in[5];
  const float* b_ih      = (const float*)d_in[6];
  const float* b_hh      = (const float*)d_in[7];
  const float* Wc  = (const float*)d_in[8];  const float* bc  = (const float*)d_in[9];
  const float* Wsh = (const float*)d_in[10]; const float* bsh = (const float*)d_in[11];
  const float* Wa  = (const float*)d_in[12]; const float* ba  = (const float*)d_in[13];
  const float* Wl  = (const float*)d_in[14]; const float* bl  = (const float*)d_in[15];
  const float* Wr  = (const float*)d_in[16]; const float* br  = (const float*)d_in[17];
  const float* Wr1 = (const float*)d_in[18]; const float* br1 = (const float*)d_in[19];
  const float* Wr2 = (const float*)d_in[20]; const float* br2 = (const float*)d_in[21];

  const int B  = in_sizes[0] / 64;   // 16384
  const int NV = in_sizes[3] / 64;   // 32001

  // workspace: embedW (NV*256 f32 ~31.3MB) | eOut (B*64 ~4MB) | attL (B*25 ~1.6MB) | wt (64KB)
  float* embedWG = (float*)d_ws;
  float* eOut    = embedWG + (size_t)NV * 256;
  float* attL    = eOut + (size_t)B * 64;
  float* wtbuf   = attL + (size_t)B * 25;
  float* out     = (float*)d_out;

  k_embedw<<<(NV + 125) / 126, 1024, 0, stream>>>(embed, W_ih, b_ih, b_hh, embedWG, NV);
  k_wt<<<16, 1024, 0, stream>>>(W_hh, wtbuf);
  k_lstm64<<<B / 64, 1024, 0, stream>>>(inst, wtbuf, embedWG, eOut);
  {
    int total = B * 25;
    k_attlog<<<(total + 255) / 256, 256, 0, stream>>>(eOut, canvas, Wr1, br1, Wr2, br2,
                                                      attL, total);
  }
  k_heads<<<(B + 255) / 256, 256, 0, stream>>>(eOut, canvas, inst_type,
                                               Wc, bc, Wsh, bsh, Wa, ba, Wl, bl, Wr, br,
                                               attL, out, B);
}